// Round 4
// baseline (635.268 us; speedup 1.0000x reference)
//
#include <hip/hip_runtime.h>
#include <math.h>

// ---------- helpers ----------

__device__ inline unsigned fenc(float f) {
    unsigned u = __float_as_uint(f);
    return (u & 0x80000000u) ? ~u : (u | 0x80000000u);
}
__device__ inline float fdec(unsigned u) {
    return __uint_as_float((u & 0x80000000u) ? (u ^ 0x80000000u) : ~u);
}

__device__ inline float wrsum(float v) {
    #pragma unroll
    for (int m = 32; m; m >>= 1) v += __shfl_xor(v, m, 64);
    return v;
}
__device__ inline float wrmax(float v) {
    #pragma unroll
    for (int m = 32; m; m >>= 1) v = fmaxf(v, __shfl_xor(v, m, 64));
    return v;
}

// ---------- GEMM 1 + fused scores1.  h1p[n][dd][h] permuted layout ----------
__global__ __launch_bounds__(256) void gemm1_kernel(const float* __restrict__ x,
                                                    const float* __restrict__ W,
                                                    const float* __restrict__ a_src,
                                                    const float* __restrict__ a_dst,
                                                    float* __restrict__ h1p,
                                                    float* __restrict__ ssrc,
                                                    float* __restrict__ sdst, int N) {
    __shared__ float xs[16 * 128];      // staged x tile (reused as partial buf)
    __shared__ float ss[16 * 257];      // acc transpose for score reduction
    int base = blockIdx.x * 16;
    int tid = threadIdx.x;
    const float4* xv = (const float4*)(x + (size_t)base * 128);
    float4* xsv = (float4*)xs;
    #pragma unroll
    for (int i = tid; i < 512; i += 256) {
        int n = base + (i >> 5);
        xsv[i] = (n < N) ? xv[i] : make_float4(0.f, 0.f, 0.f, 0.f);
    }
    __syncthreads();
    float acc[16];
    #pragma unroll
    for (int j = 0; j < 16; j++) acc[j] = 0.f;
    for (int k = 0; k < 128; k += 4) {
        float w0 = W[k * 256 + tid];
        float w1 = W[(k + 1) * 256 + tid];
        float w2 = W[(k + 2) * 256 + tid];
        float w3 = W[(k + 3) * 256 + tid];
        #pragma unroll
        for (int j = 0; j < 16; j++) {
            float4 xj = *(const float4*)(xs + j * 128 + k);
            acc[j] += xj.x * w0 + xj.y * w1 + xj.z * w2 + xj.w * w3;
        }
    }
    int dd = tid & 63, hh = tid >> 6;
    #pragma unroll
    for (int j = 0; j < 16; j++) {
        int n = base + j;
        if (n < N) h1p[(size_t)n * 256 + dd * 4 + hh] = acc[j];
    }
    // ---- scores via LDS transpose + partial sums ----
    #pragma unroll
    for (int j = 0; j < 16; j++) ss[j * 257 + tid] = acc[j];
    __syncthreads();
    int j = tid & 15, hh2 = (tid >> 4) & 3, which = (tid >> 6) & 1, half = tid >> 7;
    const float* av = which ? a_dst : a_src;
    int cbase = hh2 * 64 + half * 32;
    float sum = 0.f;
    #pragma unroll
    for (int i = 0; i < 32; i++) sum += ss[j * 257 + cbase + i] * av[cbase + i];
    xs[tid] = sum;            // xs reused as partial buffer
    __syncthreads();
    if (half == 0) {
        float tot = sum + xs[tid + 128];
        int n = base + j;
        if (n < N) (which ? sdst : ssrc)[n * 4 + hh2] = tot;
    }
}

// ---------- GEMM 2 + fused scores2: h2[N,64] = x2[N,256] @ W2[256,64] ----------
__global__ __launch_bounds__(256) void gemm2_kernel(const float* __restrict__ x2,
                                                    const float* __restrict__ W,
                                                    const float* __restrict__ a_src,
                                                    const float* __restrict__ a_dst,
                                                    float* __restrict__ h2,
                                                    float* __restrict__ ssrc,
                                                    float* __restrict__ sdst, int N) {
    __shared__ float xs[16 * 256];
    int base = blockIdx.x * 16;
    int tid = threadIdx.x;
    const float4* xv = (const float4*)(x2 + (size_t)base * 256);
    float4* xsv = (float4*)xs;
    #pragma unroll
    for (int i = tid; i < 1024; i += 256) {
        int n = base + (i >> 6);
        xsv[i] = (n < N) ? xv[i] : make_float4(0.f, 0.f, 0.f, 0.f);
    }
    __syncthreads();
    int c = tid & 63, sub = tid >> 6;
    float acc[4] = {0.f, 0.f, 0.f, 0.f};
    for (int k = 0; k < 256; k += 4) {
        float w0 = W[k * 64 + c];
        float w1 = W[(k + 1) * 64 + c];
        float w2 = W[(k + 2) * 64 + c];
        float w3 = W[(k + 3) * 64 + c];
        #pragma unroll
        for (int j = 0; j < 4; j++) {
            float4 xj = *(const float4*)(xs + (sub + 4 * j) * 256 + k);
            acc[j] += xj.x * w0 + xj.y * w1 + xj.z * w2 + xj.w * w3;
        }
    }
    float as = a_src[c], ad = a_dst[c];
    #pragma unroll
    for (int j = 0; j < 4; j++) {
        int n = base + sub + 4 * j;
        if (n < N) h2[(size_t)n * 64 + c] = acc[j];
        float ps = wrsum(acc[j] * as);
        float pd = wrsum(acc[j] * ad);
        if (c == 0 && n < N) { ssrc[n] = ps; sdst[n] = pd; }
    }
}

// ---------- CSR build ----------
__global__ __launch_bounds__(256) void hist_kernel(const int* __restrict__ ei,
                                                   int* __restrict__ deg, int E, int Etot) {
    int i = blockIdx.x * 256 + threadIdx.x;
    if (i >= Etot) return;
    int d = (i < E) ? ei[E + i] : (i - E);
    atomicAdd(&deg[d], 1);
}

__global__ __launch_bounds__(256) void chunksum_kernel(const int* __restrict__ deg,
                                                       int* __restrict__ csum, int M) {
    __shared__ int sm[256];
    int t = blockIdx.x * 256 + threadIdx.x;
    sm[threadIdx.x] = (t < M) ? deg[t] : 0;
    __syncthreads();
    for (int off = 128; off > 0; off >>= 1) {
        if (threadIdx.x < off) sm[threadIdx.x] += sm[threadIdx.x + off];
        __syncthreads();
    }
    if (threadIdx.x == 0) csum[blockIdx.x] = sm[0];
}

__global__ __launch_bounds__(256) void scanchunks_kernel(const int* __restrict__ csum,
                                                         int* __restrict__ coffset, int nchunks) {
    __shared__ int sm[256];
    int v = (threadIdx.x < nchunks) ? csum[threadIdx.x] : 0;
    sm[threadIdx.x] = v;
    __syncthreads();
    for (int off = 1; off < 256; off <<= 1) {
        int a = (threadIdx.x >= off) ? sm[threadIdx.x - off] : 0;
        __syncthreads();
        sm[threadIdx.x] += a;
        __syncthreads();
    }
    coffset[threadIdx.x] = sm[threadIdx.x] - v;
}

__global__ __launch_bounds__(256) void rowptr_kernel(const int* __restrict__ deg,
                                                     const int* __restrict__ coffset,
                                                     int* __restrict__ rowptr,
                                                     int* __restrict__ cursor, int M, int N) {
    __shared__ int sm[256];
    int t = blockIdx.x * 256 + threadIdx.x;
    int v = (t < M) ? deg[t] : 0;
    sm[threadIdx.x] = v;
    __syncthreads();
    for (int off = 1; off < 256; off <<= 1) {
        int a = (threadIdx.x >= off) ? sm[threadIdx.x - off] : 0;
        __syncthreads();
        sm[threadIdx.x] += a;
        __syncthreads();
    }
    if (t < M) {
        int rp = coffset[blockIdx.x] + sm[threadIdx.x] - v;
        rowptr[t] = rp;
        if (t < N) cursor[t] = rp;
    }
}

__global__ __launch_bounds__(256) void scatter_kernel(const int* __restrict__ ei,
                                                      int* __restrict__ cursor,
                                                      int* __restrict__ srcbuf, int E, int Etot) {
    int i = blockIdx.x * 256 + threadIdx.x;
    if (i >= Etot) return;
    int s, d;
    if (i < E) { s = ei[i]; d = ei[E + i]; } else { s = d = i - E; }
    int pos = atomicAdd(&cursor[d], 1);
    srcbuf[pos] = s;
}

// ---------- layer-1 aggregation: wave/dst, lane-parallel weights + ILP gather ----------
__global__ __launch_bounds__(256) void agg1_kernel(const int* __restrict__ rowptr,
                                                   const int* __restrict__ srcbuf,
                                                   const float* __restrict__ ssrc,
                                                   const float* __restrict__ sdst,
                                                   const float* __restrict__ h1p,
                                                   const float* __restrict__ b1,
                                                   float* __restrict__ x2, int N) {
    __shared__ int    s_sh[4][64];
    __shared__ float4 w_sh[4][64];
    int lane = threadIdx.x & 63, w = threadIdx.x >> 6;
    int d = blockIdx.x * 4 + w;
    if (d >= N) return;
    int row = rowptr[d], end = rowptr[d + 1];
    float4 sd = *(const float4*)(sdst + d * 4);
    float m0 = -INFINITY, m1 = -INFINITY, m2 = -INFINITY, m3 = -INFINITY;
    float l0 = 0.f, l1 = 0.f, l2 = 0.f, l3 = 0.f;
    float a0 = 0.f, a1 = 0.f, a2 = 0.f, a3 = 0.f;

    for (int base = row; base < end; base += 64) {
        int cnt = min(64, end - base);
        bool valid = lane < cnt;
        int s = valid ? srcbuf[base + lane] : 0;
        float4 ss = *(const float4*)(ssrc + s * 4);
        float e0 = ss.x + sd.x, e1 = ss.y + sd.y, e2 = ss.z + sd.z, e3 = ss.w + sd.w;
        e0 = e0 > 0.f ? e0 : 0.2f * e0;  e1 = e1 > 0.f ? e1 : 0.2f * e1;
        e2 = e2 > 0.f ? e2 : 0.2f * e2;  e3 = e3 > 0.f ? e3 : 0.2f * e3;
        if (!valid) { e0 = e1 = e2 = e3 = -INFINITY; }
        float nm0 = fmaxf(m0, wrmax(e0)), nm1 = fmaxf(m1, wrmax(e1));
        float nm2 = fmaxf(m2, wrmax(e2)), nm3 = fmaxf(m3, wrmax(e3));
        float sc0 = __expf(m0 - nm0), sc1 = __expf(m1 - nm1);
        float sc2 = __expf(m2 - nm2), sc3 = __expf(m3 - nm3);
        float w0 = __expf(e0 - nm0), w1 = __expf(e1 - nm1);
        float w2 = __expf(e2 - nm2), w3 = __expf(e3 - nm3);
        l0 = l0 * sc0 + wrsum(w0);  l1 = l1 * sc1 + wrsum(w1);
        l2 = l2 * sc2 + wrsum(w2);  l3 = l3 * sc3 + wrsum(w3);
        a0 *= sc0; a1 *= sc1; a2 *= sc2; a3 *= sc3;
        m0 = nm0; m1 = nm1; m2 = nm2; m3 = nm3;
        s_sh[w][lane] = s;
        w_sh[w][lane] = make_float4(w0, w1, w2, w3);
        // wave-private LDS; lockstep wave, no barrier needed
        int cnt4 = (cnt + 3) & ~3;
        for (int j = 0; j < cnt4; j += 4) {
            int sj0 = s_sh[w][j], sj1 = s_sh[w][j + 1], sj2 = s_sh[w][j + 2], sj3 = s_sh[w][j + 3];
            float4 wj0 = w_sh[w][j], wj1 = w_sh[w][j + 1], wj2 = w_sh[w][j + 2], wj3 = w_sh[w][j + 3];
            float4 h0 = *(const float4*)(h1p + (size_t)sj0 * 256 + lane * 4);
            float4 h1 = *(const float4*)(h1p + (size_t)sj1 * 256 + lane * 4);
            float4 h2 = *(const float4*)(h1p + (size_t)sj2 * 256 + lane * 4);
            float4 h3 = *(const float4*)(h1p + (size_t)sj3 * 256 + lane * 4);
            a0 += wj0.x * h0.x; a1 += wj0.y * h0.y; a2 += wj0.z * h0.z; a3 += wj0.w * h0.w;
            a0 += wj1.x * h1.x; a1 += wj1.y * h1.y; a2 += wj1.z * h1.z; a3 += wj1.w * h1.w;
            a0 += wj2.x * h2.x; a1 += wj2.y * h2.y; a2 += wj2.z * h2.z; a3 += wj2.w * h2.w;
            a0 += wj3.x * h3.x; a1 += wj3.y * h3.y; a2 += wj3.z * h3.z; a3 += wj3.w * h3.w;
        }
    }
    float v0 = a0 / l0 + b1[lane];
    float v1 = a1 / l1 + b1[64 + lane];
    float v2 = a2 / l2 + b1[128 + lane];
    float v3 = a3 / l3 + b1[192 + lane];
    v0 = v0 > 0.f ? v0 : __expf(v0) - 1.f;
    v1 = v1 > 0.f ? v1 : __expf(v1) - 1.f;
    v2 = v2 > 0.f ? v2 : __expf(v2) - 1.f;
    v3 = v3 > 0.f ? v3 : __expf(v3) - 1.f;
    float* xp = x2 + (size_t)d * 256;
    xp[lane] = v0; xp[64 + lane] = v1; xp[128 + lane] = v2; xp[192 + lane] = v3;
}

// ---------- layer-2 aggregation (4 edges per gather instr) + fused global min ----------
__global__ __launch_bounds__(256) void agg2_kernel(const int* __restrict__ rowptr,
                                                   const int* __restrict__ srcbuf,
                                                   const float* __restrict__ ssrc,
                                                   const float* __restrict__ sdst,
                                                   const float* __restrict__ h2,
                                                   const float* __restrict__ b2,
                                                   unsigned* __restrict__ minenc, int N) {
    __shared__ int    s_sh[4][64];
    __shared__ float  w_sh[4][64];
    __shared__ float4 t_sh[4][16];
    int lane = threadIdx.x & 63, w = threadIdx.x >> 6;
    int q = lane & 15, eo = lane >> 4;     // dim-quad, edge-in-group
    int d = blockIdx.x * 4 + w;
    float out = INFINITY;
    if (d < N) {
        int row = rowptr[d], end = rowptr[d + 1];
        float sdv = sdst[d];
        float m = -INFINITY, l = 0.f;
        float4 acc = make_float4(0.f, 0.f, 0.f, 0.f);
        for (int base = row; base < end; base += 64) {
            int cnt = min(64, end - base);
            bool valid = lane < cnt;
            int s = valid ? srcbuf[base + lane] : 0;
            float e = ssrc[s] + sdv;
            e = e > 0.f ? e : 0.2f * e;
            if (!valid) e = -INFINITY;
            float nm = fmaxf(m, wrmax(e));
            float sc = __expf(m - nm);
            float wt = __expf(e - nm);      // = 0 for invalid lanes
            l = l * sc + wrsum(wt);
            acc.x *= sc; acc.y *= sc; acc.z *= sc; acc.w *= sc;
            m = nm;
            s_sh[w][lane] = s;
            w_sh[w][lane] = wt;
            // each lane gathers float4 of h2 row: 4 edges per instruction
            int cnt8 = (cnt + 7) & ~7;
            for (int j = 0; j < cnt8; j += 8) {
                int e0 = j + eo, e1 = j + 4 + eo;
                int s0 = s_sh[w][e0], s1 = s_sh[w][e1];
                float w0 = w_sh[w][e0], w1 = w_sh[w][e1];
                float4 h0 = *(const float4*)(h2 + (size_t)s0 * 64 + q * 4);
                float4 h1 = *(const float4*)(h2 + (size_t)s1 * 64 + q * 4);
                acc.x += w0 * h0.x + w1 * h1.x;
                acc.y += w0 * h0.y + w1 * h1.y;
                acc.z += w0 * h0.z + w1 * h1.z;
                acc.w += w0 * h0.w + w1 * h1.w;
            }
        }
        // reduce over the 4 edge-groups (lanes q, 16+q, 32+q, 48+q)
        #pragma unroll
        for (int mask = 16; mask <= 32; mask <<= 1) {
            acc.x += __shfl_xor(acc.x, mask, 64);
            acc.y += __shfl_xor(acc.y, mask, 64);
            acc.z += __shfl_xor(acc.z, mask, 64);
            acc.w += __shfl_xor(acc.w, mask, 64);
        }
        if (lane < 16) t_sh[w][lane] = acc;   // wave-private, lockstep
        float accd = ((const float*)&t_sh[w][0])[lane];
        out = accd / l + b2[lane];
    }
    __shared__ float sm[256];
    sm[threadIdx.x] = out;
    __syncthreads();
    if (w == 0) {
        float v = fminf(fminf(sm[lane], sm[64 + lane]), fminf(sm[128 + lane], sm[192 + lane]));
        atomicMin(&minenc[lane], fenc(v));
    }
}

__global__ void decode_kernel(const unsigned* __restrict__ minenc, float* __restrict__ out) {
    int d = threadIdx.x;
    if (d < 64) out[d] = fdec(minenc[d]);
}

// ---------- launch ----------
extern "C" void kernel_launch(void* const* d_in, const int* in_sizes, int n_in,
                              void* d_out, int out_size, void* d_ws, size_t ws_size,
                              hipStream_t stream) {
    const float* x      = (const float*)d_in[0];
    const int*   ei     = (const int*)d_in[1];
    const float* W1     = (const float*)d_in[2];
    const float* a_src1 = (const float*)d_in[3];
    const float* a_dst1 = (const float*)d_in[4];
    const float* b1     = (const float*)d_in[5];
    const float* W2     = (const float*)d_in[6];
    const float* a_src2 = (const float*)d_in[7];
    const float* a_dst2 = (const float*)d_in[8];
    const float* b2     = (const float*)d_in[9];
    float* out = (float*)d_out;

    const int N = in_sizes[0] / 128;
    const int E = in_sizes[1] / 2;
    const int Etot = E + N;
    const int M = N + 1;
    const int nchunks = (M + 255) / 256;   // <= 256 for N <= ~65k

    float* ws = (float*)d_ws;
    float* h1p    = ws;                               // N*256 (permuted [n][dd][h])
    float* x2     = h1p + (size_t)N * 256;            // N*256
    float* h2     = x2 + (size_t)N * 256;             // N*64
    float* ssrc1  = h2 + (size_t)N * 64;              // 4N (16B aligned)
    float* sdst1  = ssrc1 + (size_t)N * 4;            // 4N
    float* ssrc2  = sdst1 + (size_t)N * 4;            // N
    float* sdst2  = ssrc2 + N;                        // N
    int*   deg    = (int*)(sdst2 + N);                // N+1
    int*   rowptr = deg + M;                          // N+1
    int*   cursor = rowptr + M;                       // N
    int*   csum   = cursor + N;                       // 256
    int*   coff   = csum + 256;                       // 256
    int*   srcbuf = coff + 256;                       // Etot
    unsigned* minenc = (unsigned*)(srcbuf + Etot);    // 64

    hipMemsetAsync(deg, 0, (size_t)M * 4, stream);
    hipMemsetAsync(minenc, 0xFF, 64 * 4, stream);

    int nb16 = (N + 15) / 16;
    gemm1_kernel<<<nb16, 256, 0, stream>>>(x, W1, a_src1, a_dst1, h1p, ssrc1, sdst1, N);

    hist_kernel<<<(Etot + 255) / 256, 256, 0, stream>>>(ei, deg, E, Etot);
    chunksum_kernel<<<nchunks, 256, 0, stream>>>(deg, csum, M);
    scanchunks_kernel<<<1, 256, 0, stream>>>(csum, coff, nchunks);
    rowptr_kernel<<<nchunks, 256, 0, stream>>>(deg, coff, rowptr, cursor, M, N);
    scatter_kernel<<<(Etot + 255) / 256, 256, 0, stream>>>(ei, cursor, srcbuf, E, Etot);

    agg1_kernel<<<(N + 3) / 4, 256, 0, stream>>>(rowptr, srcbuf, ssrc1, sdst1, h1p, b1, x2, N);
    gemm2_kernel<<<nb16, 256, 0, stream>>>(x2, W2, a_src2, a_dst2, h2, ssrc2, sdst2, N);
    agg2_kernel<<<(N + 3) / 4, 256, 0, stream>>>(rowptr, srcbuf, ssrc2, sdst2, h2, b2, minenc, N);
    decode_kernel<<<1, 64, 0, stream>>>(minenc, out);
}